// Round 3
// baseline (205.780 us; speedup 1.0000x reference)
//
#include <hip/hip_runtime.h>
#include <hip/hip_bf16.h>
#include <math.h>

// Problem constants (match reference)
#define H 4
#define C 32
#define HC 128
#define F_IN 7
#define NEG_SLOPE 0.2f

// ---------------------------------------------------------------------------
// K1: per-node attention logits a_src[i][h], a_dst[i][h].
// One wave (64 lanes) per node; lane owns channels c0=2*lane, c0+1.
// h[i][c] = sum_k x[i][k] * W[k][c] computed on the fly.
// ---------------------------------------------------------------------------
__global__ __launch_bounds__(256) void node_logits_kernel(
    const float* __restrict__ x, const float* __restrict__ W,
    const float* __restrict__ att_src, const float* __restrict__ att_dst,
    float* __restrict__ a_src, float* __restrict__ a_dst, int n)
{
    int wave = threadIdx.x >> 6;
    int lane = threadIdx.x & 63;
    int i = blockIdx.x * 4 + wave;
    if (i >= n) return;
    int c0 = lane * 2;
    int head = lane >> 4;

    const float* xi = x + i * F_IN;
    float xk[F_IN];
#pragma unroll
    for (int k = 0; k < F_IN; k++) xk[k] = xi[k];

    float h0 = 0.f, h1 = 0.f;
#pragma unroll
    for (int k = 0; k < F_IN; k++) {
        h0 = fmaf(xk[k], W[k * HC + c0], h0);
        h1 = fmaf(xk[k], W[k * HC + c0 + 1], h1);
    }
    float ps = h0 * att_src[c0] + h1 * att_src[c0 + 1];
    float pd = h0 * att_dst[c0] + h1 * att_dst[c0 + 1];
    // reduce across the 16 lanes of this head
#pragma unroll
    for (int d = 1; d < 16; d <<= 1) {
        ps += __shfl_xor(ps, d);
        pd += __shfl_xor(pd, d);
    }
    if ((lane & 15) == 0) {
        a_src[i * H + head] = ps;
        a_dst[i * H + head] = pd;
    }
}

// ---------------------------------------------------------------------------
// K2: flag queried destination nodes
// ---------------------------------------------------------------------------
__global__ void flag_kernel(const int* __restrict__ ids, int* __restrict__ flag, int n_ids)
{
    int q = blockIdx.x * 256 + threadIdx.x;
    if (q < n_ids) flag[ids[q]] = 1;
}

// ---------------------------------------------------------------------------
// K3: in-degree histogram (flagged dsts only)
// ---------------------------------------------------------------------------
__global__ void hist_kernel(const int* __restrict__ ei, const int* __restrict__ flag,
                            int* __restrict__ counts, int E)
{
    int e = blockIdx.x * 256 + threadIdx.x;
    if (e < E) {
        int dst = ei[E + e];
        if (flag[dst]) atomicAdd(&counts[dst], 1);
    }
}

// ---------------------------------------------------------------------------
// K4a/b/c: exclusive scan of counts -> offsets (3-kernel classic)
// ---------------------------------------------------------------------------
#define SCAN_B 1024
__global__ __launch_bounds__(SCAN_B) void scan_part(
    const int* __restrict__ counts, int* __restrict__ offsets,
    int* __restrict__ bsums, int n)
{
    __shared__ int tmp[SCAN_B];
    int tid = threadIdx.x;
    int gid = blockIdx.x * SCAN_B + tid;
    int v = (gid < n) ? counts[gid] : 0;
    tmp[tid] = v;
    __syncthreads();
    for (int ofs = 1; ofs < SCAN_B; ofs <<= 1) {
        int t = (tid >= ofs) ? tmp[tid - ofs] : 0;
        __syncthreads();
        tmp[tid] += t;
        __syncthreads();
    }
    if (gid < n) offsets[gid] = tmp[tid] - v;  // exclusive
    if (tid == SCAN_B - 1) bsums[blockIdx.x] = tmp[tid];
}

__global__ void scan_mid(int* __restrict__ bsums, int nb)
{
    if (threadIdx.x == 0 && blockIdx.x == 0) {
        int acc = 0;
        for (int i = 0; i < nb; i++) { int v = bsums[i]; bsums[i] = acc; acc += v; }
    }
}

__global__ __launch_bounds__(SCAN_B) void scan_add(
    int* __restrict__ offsets, int* __restrict__ cursor,
    const int* __restrict__ bsums, int n)
{
    int gid = blockIdx.x * SCAN_B + threadIdx.x;
    if (gid < n) {
        int o = offsets[gid] + bsums[blockIdx.x];
        offsets[gid] = o;
        cursor[gid] = o;
    }
}

// ---------------------------------------------------------------------------
// K5: scatter src ids into compact CSR
// ---------------------------------------------------------------------------
__global__ void scatter_kernel(const int* __restrict__ ei, const int* __restrict__ flag,
                               int* __restrict__ cursor, int* __restrict__ csr_src, int E)
{
    int e = blockIdx.x * 256 + threadIdx.x;
    if (e < E) {
        int dst = ei[E + e];
        if (flag[dst]) {
            int pos = atomicAdd(&cursor[dst], 1);
            csr_src[pos] = ei[e];
        }
    }
}

// ---------------------------------------------------------------------------
// K6: per-queried-id GAT aggregation + LayerNorm + classifier + softmax.
// One wave per id. Lane owns channels c0=2*lane, c0+1; head = lane>>4.
// ---------------------------------------------------------------------------
__global__ __launch_bounds__(256) void gat_out_kernel(
    const float* __restrict__ x, const float* __restrict__ W,
    const float* __restrict__ a_src, const float* __restrict__ a_dst,
    const float* __restrict__ gat_bias,
    const float* __restrict__ ln_w, const float* __restrict__ ln_b,
    const float* __restrict__ lin_W, const float* __restrict__ lin_b,
    const int* __restrict__ csr_src, const int* __restrict__ offsets,
    const int* __restrict__ counts, const int* __restrict__ ids,
    float* __restrict__ out, int n_ids)
{
    int wave = threadIdx.x >> 6;
    int lane = threadIdx.x & 63;
    int q = blockIdx.x * 4 + wave;
    if (q >= n_ids) return;
    int i = ids[q];
    int c0 = lane * 2;
    int head = lane >> 4;

    // W columns for my two channels
    float w0[F_IN], w1[F_IN];
#pragma unroll
    for (int k = 0; k < F_IN; k++) {
        w0[k] = W[k * HC + c0];
        w1[k] = W[k * HC + c0 + 1];
    }
    float ad = a_dst[i * H + head];
    int off = offsets[i];
    int deg = counts[i];

    // phase A: segment max of leaky_relu logits (per head, redundant in 16 lanes)
    float m = -INFINITY;
    for (int e = 0; e < deg; e++) {
        int s = csr_src[off + e];
        float al = a_src[s * H + head] + ad;
        al = (al >= 0.f) ? al : NEG_SLOPE * al;
        m = fmaxf(m, al);
    }

    // phase B: exp weights, denominator, weighted accumulation of h[src]
    float denom = 0.f, acc0 = 0.f, acc1 = 0.f;
    for (int e = 0; e < deg; e++) {
        int s = csr_src[off + e];
        float al = a_src[s * H + head] + ad;
        al = (al >= 0.f) ? al : NEG_SLOPE * al;
        float p = __expf(al - m);
        denom += p;
        const float* xs = x + s * F_IN;
        float h0 = 0.f, h1 = 0.f;
#pragma unroll
        for (int k = 0; k < F_IN; k++) {
            float xv = xs[k];
            h0 = fmaf(xv, w0[k], h0);
            h1 = fmaf(xv, w1[k], h1);
        }
        acc0 = fmaf(p, h0, acc0);
        acc1 = fmaf(p, h1, acc1);
    }
    float inv = 1.f / (denom + 1e-16f);
    float v0 = acc0 * inv + gat_bias[c0];
    float v1 = acc1 * inv + gat_bias[c0 + 1];

    // LayerNorm over 128 channels (full-wave butterfly reductions)
    float ssum = v0 + v1;
#pragma unroll
    for (int d = 1; d < 64; d <<= 1) ssum += __shfl_xor(ssum, d);
    float mu = ssum * (1.f / 128.f);
    float d0 = v0 - mu, d1 = v1 - mu;
    float vsum = d0 * d0 + d1 * d1;
#pragma unroll
    for (int d = 1; d < 64; d <<= 1) vsum += __shfl_xor(vsum, d);
    float rstd = rsqrtf(vsum * (1.f / 128.f) + 1e-5f);
    float y0 = d0 * rstd * ln_w[c0] + ln_b[c0];
    float y1 = d1 * rstd * ln_w[c0 + 1] + ln_b[c0 + 1];

    // classifier: 7 logits, reduce each across the wave
    float lg[F_IN];
#pragma unroll
    for (int j = 0; j < F_IN; j++)
        lg[j] = y0 * lin_W[c0 * F_IN + j] + y1 * lin_W[(c0 + 1) * F_IN + j];
#pragma unroll
    for (int j = 0; j < F_IN; j++) {
#pragma unroll
        for (int d = 1; d < 64; d <<= 1) lg[j] += __shfl_xor(lg[j], d);
    }
    // softmax over 7 classes (all lanes have full logits); lanes 0..6 write
#pragma unroll
    for (int j = 0; j < F_IN; j++) lg[j] += lin_b[j];
    float mx = lg[0];
#pragma unroll
    for (int j = 1; j < F_IN; j++) mx = fmaxf(mx, lg[j]);
    float se = 0.f;
#pragma unroll
    for (int j = 0; j < F_IN; j++) se += __expf(lg[j] - mx);
    if (lane < F_IN) {
        out[q * F_IN + lane] = __expf(lg[lane] - mx) / se;
    }
}

// ---------------------------------------------------------------------------
extern "C" void kernel_launch(void* const* d_in, const int* in_sizes, int n_in,
                              void* d_out, int out_size, void* d_ws, size_t ws_size,
                              hipStream_t stream)
{
    const float* x        = (const float*)d_in[0];
    // d_in[1] = edge_weight (unused by GATConv with edge_dim=None)
    const float* W        = (const float*)d_in[2];
    const float* att_src  = (const float*)d_in[3];
    const float* att_dst  = (const float*)d_in[4];
    const float* gat_bias = (const float*)d_in[5];
    const float* ln_w     = (const float*)d_in[6];
    const float* ln_b     = (const float*)d_in[7];
    const float* lin_W    = (const float*)d_in[8];
    const float* lin_b    = (const float*)d_in[9];
    const int*   ei       = (const int*)d_in[10];
    const int*   ids      = (const int*)d_in[11];

    const int N     = in_sizes[0] / F_IN;
    const int E     = in_sizes[10] / 2;
    const int n_ids = in_sizes[11];
    float* out = (float*)d_out;

    // workspace layout
    char* ws = (char*)d_ws;
    float* a_src = (float*)ws;                 ws += (size_t)N * H * sizeof(float);
    float* a_dst = (float*)ws;                 ws += (size_t)N * H * sizeof(float);
    int* flag    = (int*)ws;                   ws += (size_t)N * sizeof(int);
    int* counts  = (int*)ws;                   ws += (size_t)N * sizeof(int);
    int* offsets = (int*)ws;                   ws += (size_t)N * sizeof(int);
    int* cursor  = (int*)ws;                   ws += (size_t)N * sizeof(int);
    int* bsums   = (int*)ws;                   ws += (size_t)1024 * sizeof(int);
    int* csr_src = (int*)ws;                   ws += (size_t)E * sizeof(int);

    // zero flag + counts (adjacent -> one memset)
    hipMemsetAsync(flag, 0, (size_t)2 * N * sizeof(int), stream);

    node_logits_kernel<<<(N + 3) / 4, 256, 0, stream>>>(x, W, att_src, att_dst, a_src, a_dst, N);
    flag_kernel<<<(n_ids + 255) / 256, 256, 0, stream>>>(ids, flag, n_ids);
    hist_kernel<<<(E + 255) / 256, 256, 0, stream>>>(ei, flag, counts, E);

    int nblk = (N + SCAN_B - 1) / SCAN_B;
    scan_part<<<nblk, SCAN_B, 0, stream>>>(counts, offsets, bsums, N);
    scan_mid<<<1, 64, 0, stream>>>(bsums, nblk);
    scan_add<<<nblk, SCAN_B, 0, stream>>>(offsets, cursor, bsums, N);

    scatter_kernel<<<(E + 255) / 256, 256, 0, stream>>>(ei, flag, cursor, csr_src, E);

    gat_out_kernel<<<(n_ids + 3) / 4, 256, 0, stream>>>(
        x, W, a_src, a_dst, gat_bias, ln_w, ln_b, lin_W, lin_b,
        csr_src, offsets, counts, ids, out, n_ids);
}

// Round 4
// 190.759 us; speedup vs baseline: 1.0787x; 1.0787x over previous
//
#include <hip/hip_runtime.h>
#include <hip/hip_bf16.h>
#include <math.h>

// Problem constants (match reference)
#define H 4
#define C 32
#define HC 128
#define F_IN 7
#define NEG_SLOPE 0.2f

__device__ __forceinline__ float leaky(float v) { return v >= 0.f ? v : NEG_SLOPE * v; }

// ---------------------------------------------------------------------------
// K1: per-node attention logits a_src[i][h], a_dst[i][h]  (+ fused id flagging)
// One wave (64 lanes) per node; lane owns channels c0=2*lane, c0+1.
// ---------------------------------------------------------------------------
__global__ __launch_bounds__(256) void node_logits_kernel(
    const float* __restrict__ x, const float* __restrict__ W,
    const float* __restrict__ att_src, const float* __restrict__ att_dst,
    float* __restrict__ a_src, float* __restrict__ a_dst,
    const int* __restrict__ ids, int* __restrict__ flag, int n_ids, int n)
{
    int gt = blockIdx.x * 256 + threadIdx.x;
    if (gt < n_ids) flag[ids[gt]] = 1;   // fused: flag queried nodes

    int wave = threadIdx.x >> 6;
    int lane = threadIdx.x & 63;
    int i = blockIdx.x * 4 + wave;
    if (i >= n) return;
    int c0 = lane * 2;
    int head = lane >> 4;

    const float* xi = x + i * F_IN;
    float xk[F_IN];
#pragma unroll
    for (int k = 0; k < F_IN; k++) xk[k] = xi[k];

    float h0 = 0.f, h1 = 0.f;
#pragma unroll
    for (int k = 0; k < F_IN; k++) {
        h0 = fmaf(xk[k], W[k * HC + c0], h0);
        h1 = fmaf(xk[k], W[k * HC + c0 + 1], h1);
    }
    float ps = h0 * att_src[c0] + h1 * att_src[c0 + 1];
    float pd = h0 * att_dst[c0] + h1 * att_dst[c0 + 1];
#pragma unroll
    for (int d = 1; d < 16; d <<= 1) {
        ps += __shfl_xor(ps, d);
        pd += __shfl_xor(pd, d);
    }
    if ((lane & 15) == 0) {
        a_src[i * H + head] = ps;
        a_dst[i * H + head] = pd;
    }
}

// ---------------------------------------------------------------------------
// K3: in-degree histogram (flagged dsts only), 4 edges/thread
// ---------------------------------------------------------------------------
__global__ void hist_kernel(const int* __restrict__ ei, const int* __restrict__ flag,
                            int* __restrict__ counts, int E)
{
    int t = blockIdx.x * 256 + threadIdx.x;
    int e0 = t * 4;
    if (e0 + 3 < E && (E & 3) == 0) {
        int4 d4 = *reinterpret_cast<const int4*>(ei + (size_t)E + e0);
        if (flag[d4.x]) atomicAdd(&counts[d4.x], 1);
        if (flag[d4.y]) atomicAdd(&counts[d4.y], 1);
        if (flag[d4.z]) atomicAdd(&counts[d4.z], 1);
        if (flag[d4.w]) atomicAdd(&counts[d4.w], 1);
    } else {
        for (int e = e0; e < E && e < e0 + 4; e++) {
            int dst = ei[(size_t)E + e];
            if (flag[dst]) atomicAdd(&counts[dst], 1);
        }
    }
}

// ---------------------------------------------------------------------------
// K4a/b/c: exclusive scan of counts -> offsets
// ---------------------------------------------------------------------------
#define SCAN_B 1024
__global__ __launch_bounds__(SCAN_B) void scan_part(
    const int* __restrict__ counts, int* __restrict__ offsets,
    int* __restrict__ bsums, int n)
{
    __shared__ int tmp[SCAN_B];
    int tid = threadIdx.x;
    int gid = blockIdx.x * SCAN_B + tid;
    int v = (gid < n) ? counts[gid] : 0;
    tmp[tid] = v;
    __syncthreads();
    for (int ofs = 1; ofs < SCAN_B; ofs <<= 1) {
        int t = (tid >= ofs) ? tmp[tid - ofs] : 0;
        __syncthreads();
        tmp[tid] += t;
        __syncthreads();
    }
    if (gid < n) offsets[gid] = tmp[tid] - v;  // exclusive
    if (tid == SCAN_B - 1) bsums[blockIdx.x] = tmp[tid];
}

// parallel block-sum scan (nb <= 1024), replaces serial single-thread loop
__global__ __launch_bounds__(SCAN_B) void scan_mid(int* __restrict__ bsums, int nb)
{
    __shared__ int tmp[SCAN_B];
    int tid = threadIdx.x;
    int v = (tid < nb) ? bsums[tid] : 0;
    tmp[tid] = v;
    __syncthreads();
    for (int ofs = 1; ofs < SCAN_B; ofs <<= 1) {
        int t = (tid >= ofs) ? tmp[tid - ofs] : 0;
        __syncthreads();
        tmp[tid] += t;
        __syncthreads();
    }
    if (tid < nb) bsums[tid] = tmp[tid] - v;  // exclusive
}

__global__ __launch_bounds__(SCAN_B) void scan_add(
    int* __restrict__ offsets, int* __restrict__ cursor,
    const int* __restrict__ bsums, int n)
{
    int gid = blockIdx.x * SCAN_B + threadIdx.x;
    if (gid < n) {
        int o = offsets[gid] + bsums[blockIdx.x];
        offsets[gid] = o;
        cursor[gid] = o;
    }
}

// ---------------------------------------------------------------------------
// K5: scatter src ids into compact CSR, 4 edges/thread
// ---------------------------------------------------------------------------
__global__ void scatter_kernel(const int* __restrict__ ei, const int* __restrict__ flag,
                               int* __restrict__ cursor, int* __restrict__ csr_src, int E)
{
    int t = blockIdx.x * 256 + threadIdx.x;
    int e0 = t * 4;
    if (e0 + 3 < E && (E & 3) == 0) {
        int4 d4 = *reinterpret_cast<const int4*>(ei + (size_t)E + e0);
        int4 s4 = *reinterpret_cast<const int4*>(ei + e0);
        if (flag[d4.x]) csr_src[atomicAdd(&cursor[d4.x], 1)] = s4.x;
        if (flag[d4.y]) csr_src[atomicAdd(&cursor[d4.y], 1)] = s4.y;
        if (flag[d4.z]) csr_src[atomicAdd(&cursor[d4.z], 1)] = s4.z;
        if (flag[d4.w]) csr_src[atomicAdd(&cursor[d4.w], 1)] = s4.w;
    } else {
        for (int e = e0; e < E && e < e0 + 4; e++) {
            int dst = ei[(size_t)E + e];
            if (flag[dst]) csr_src[atomicAdd(&cursor[dst], 1)] = ei[e];
        }
    }
}

// ---------------------------------------------------------------------------
// K6: per-queried-id GAT aggregation + LayerNorm + classifier + softmax.
// One wave per id; lane = edge (parallel gathers). Weighted-x reduction first,
// single 7x2 matvec with W at the end:  sum_e p_e*(x_e@W) == (sum_e p_e*x_e)@W.
// ---------------------------------------------------------------------------
__global__ __launch_bounds__(256) void gat_out_kernel(
    const float* __restrict__ x, const float* __restrict__ W,
    const float* __restrict__ a_src, const float* __restrict__ a_dst,
    const float* __restrict__ gat_bias,
    const float* __restrict__ ln_w, const float* __restrict__ ln_b,
    const float* __restrict__ lin_W, const float* __restrict__ lin_b,
    const int* __restrict__ csr_src, const int* __restrict__ offsets,
    const int* __restrict__ counts, const int* __restrict__ ids,
    float* __restrict__ out, int n_ids)
{
    int wave = threadIdx.x >> 6;
    int lane = threadIdx.x & 63;
    int q = blockIdx.x * 4 + wave;
    if (q >= n_ids) return;
    int i = ids[q];
    int off = offsets[i];
    int deg = counts[i];

    const float4 ad = *reinterpret_cast<const float4*>(a_dst + i * 4);

    float lz[4][F_IN];   // per-lane partial: p_h * x_k
    float lden[4];       // per-lane partial: p_h
#pragma unroll
    for (int h = 0; h < 4; h++) {
        lden[h] = 0.f;
#pragma unroll
        for (int k = 0; k < F_IN; k++) lz[h][k] = 0.f;
    }

    if (deg <= 64) {
        // fast path: lane e owns edge e; everything stays in registers
        bool act = lane < deg;
        float al[4] = {-INFINITY, -INFINITY, -INFINITY, -INFINITY};
        float xk[F_IN];
#pragma unroll
        for (int k = 0; k < F_IN; k++) xk[k] = 0.f;
        if (act) {
            int s = csr_src[off + lane];
            float4 as4 = *reinterpret_cast<const float4*>(a_src + s * 4);
            al[0] = leaky(as4.x + ad.x);
            al[1] = leaky(as4.y + ad.y);
            al[2] = leaky(as4.z + ad.z);
            al[3] = leaky(as4.w + ad.w);
            const float* xs = x + s * F_IN;
#pragma unroll
            for (int k = 0; k < F_IN; k++) xk[k] = xs[k];
        }
        float m[4] = {al[0], al[1], al[2], al[3]};
#pragma unroll
        for (int d = 1; d < 64; d <<= 1) {
#pragma unroll
            for (int h = 0; h < 4; h++) m[h] = fmaxf(m[h], __shfl_xor(m[h], d));
        }
#pragma unroll
        for (int h = 0; h < 4; h++) {
            float p = act ? __expf(al[h] - m[h]) : 0.f;
            lden[h] = p;
#pragma unroll
            for (int k = 0; k < F_IN; k++) lz[h][k] = p * xk[k];
        }
    } else {
        // generic chunked two-pass (deg > 64; astronomically rare at avg deg 16)
        float m[4] = {-INFINITY, -INFINITY, -INFINITY, -INFINITY};
        for (int base = 0; base < deg; base += 64) {
            int e = base + lane;
            if (e < deg) {
                int s = csr_src[off + e];
                float4 as4 = *reinterpret_cast<const float4*>(a_src + s * 4);
                m[0] = fmaxf(m[0], leaky(as4.x + ad.x));
                m[1] = fmaxf(m[1], leaky(as4.y + ad.y));
                m[2] = fmaxf(m[2], leaky(as4.z + ad.z));
                m[3] = fmaxf(m[3], leaky(as4.w + ad.w));
            }
        }
#pragma unroll
        for (int d = 1; d < 64; d <<= 1) {
#pragma unroll
            for (int h = 0; h < 4; h++) m[h] = fmaxf(m[h], __shfl_xor(m[h], d));
        }
        for (int base = 0; base < deg; base += 64) {
            int e = base + lane;
            if (e < deg) {
                int s = csr_src[off + e];
                float4 as4 = *reinterpret_cast<const float4*>(a_src + s * 4);
                float al[4];
                al[0] = leaky(as4.x + ad.x);
                al[1] = leaky(as4.y + ad.y);
                al[2] = leaky(as4.z + ad.z);
                al[3] = leaky(as4.w + ad.w);
                float xk[F_IN];
                const float* xs = x + s * F_IN;
#pragma unroll
                for (int k = 0; k < F_IN; k++) xk[k] = xs[k];
#pragma unroll
                for (int h = 0; h < 4; h++) {
                    float p = __expf(al[h] - m[h]);
                    lden[h] += p;
#pragma unroll
                    for (int k = 0; k < F_IN; k++) lz[h][k] = fmaf(p, xk[k], lz[h][k]);
                }
            }
        }
    }

    // wave butterfly-sum of 32 values: 4 heads x (7 z + 1 denom)
#pragma unroll
    for (int d = 1; d < 64; d <<= 1) {
#pragma unroll
        for (int h = 0; h < 4; h++) {
            lden[h] += __shfl_xor(lden[h], d);
#pragma unroll
            for (int k = 0; k < F_IN; k++) lz[h][k] += __shfl_xor(lz[h][k], d);
        }
    }

    int c0 = lane * 2;
    int head = lane >> 4;
    // compile-time-indexed selects (no runtime array indexing -> no scratch)
    float den = head == 0 ? lden[0] : head == 1 ? lden[1] : head == 2 ? lden[2] : lden[3];
    float zk[F_IN];
#pragma unroll
    for (int k = 0; k < F_IN; k++)
        zk[k] = head == 0 ? lz[0][k] : head == 1 ? lz[1][k] : head == 2 ? lz[2][k] : lz[3][k];

    float inv = 1.f / (den + 1e-16f);
    float a0 = 0.f, a1 = 0.f;
#pragma unroll
    for (int k = 0; k < F_IN; k++) {
        a0 = fmaf(zk[k], W[k * HC + c0], a0);
        a1 = fmaf(zk[k], W[k * HC + c0 + 1], a1);
    }
    float v0 = a0 * inv + gat_bias[c0];
    float v1 = a1 * inv + gat_bias[c0 + 1];

    // LayerNorm over 128 channels
    float ssum = v0 + v1;
#pragma unroll
    for (int d = 1; d < 64; d <<= 1) ssum += __shfl_xor(ssum, d);
    float mu = ssum * (1.f / 128.f);
    float d0 = v0 - mu, d1 = v1 - mu;
    float vsum = d0 * d0 + d1 * d1;
#pragma unroll
    for (int d = 1; d < 64; d <<= 1) vsum += __shfl_xor(vsum, d);
    float rstd = rsqrtf(vsum * (1.f / 128.f) + 1e-5f);
    float y0 = d0 * rstd * ln_w[c0] + ln_b[c0];
    float y1 = d1 * rstd * ln_w[c0 + 1] + ln_b[c0 + 1];

    // classifier: 7 logits reduced across the wave
    float lg[F_IN];
#pragma unroll
    for (int j = 0; j < F_IN; j++)
        lg[j] = y0 * lin_W[c0 * F_IN + j] + y1 * lin_W[(c0 + 1) * F_IN + j];
#pragma unroll
    for (int j = 0; j < F_IN; j++) {
#pragma unroll
        for (int d = 1; d < 64; d <<= 1) lg[j] += __shfl_xor(lg[j], d);
    }
#pragma unroll
    for (int j = 0; j < F_IN; j++) lg[j] += lin_b[j];
    float mx = lg[0];
#pragma unroll
    for (int j = 1; j < F_IN; j++) mx = fmaxf(mx, lg[j]);
    float se = 0.f;
#pragma unroll
    for (int j = 0; j < F_IN; j++) se += __expf(lg[j] - mx);
    if (lane < F_IN) {
        out[q * F_IN + lane] = __expf(lg[lane] - mx) / se;
    }
}

// ---------------------------------------------------------------------------
extern "C" void kernel_launch(void* const* d_in, const int* in_sizes, int n_in,
                              void* d_out, int out_size, void* d_ws, size_t ws_size,
                              hipStream_t stream)
{
    const float* x        = (const float*)d_in[0];
    // d_in[1] = edge_weight (unused: edge_dim=None in GATConv)
    const float* W        = (const float*)d_in[2];
    const float* att_src  = (const float*)d_in[3];
    const float* att_dst  = (const float*)d_in[4];
    const float* gat_bias = (const float*)d_in[5];
    const float* ln_w     = (const float*)d_in[6];
    const float* ln_b     = (const float*)d_in[7];
    const float* lin_W    = (const float*)d_in[8];
    const float* lin_b    = (const float*)d_in[9];
    const int*   ei       = (const int*)d_in[10];
    const int*   ids      = (const int*)d_in[11];

    const int N     = in_sizes[0] / F_IN;
    const int E     = in_sizes[10] / 2;
    const int n_ids = in_sizes[11];
    float* out = (float*)d_out;

    // workspace layout
    char* ws = (char*)d_ws;
    float* a_src = (float*)ws;                 ws += (size_t)N * H * sizeof(float);
    float* a_dst = (float*)ws;                 ws += (size_t)N * H * sizeof(float);
    int* flag    = (int*)ws;                   ws += (size_t)N * sizeof(int);
    int* counts  = (int*)ws;                   ws += (size_t)N * sizeof(int);
    int* offsets = (int*)ws;                   ws += (size_t)N * sizeof(int);
    int* cursor  = (int*)ws;                   ws += (size_t)N * sizeof(int);
    int* bsums   = (int*)ws;                   ws += (size_t)1024 * sizeof(int);
    int* csr_src = (int*)ws;                   ws += (size_t)E * sizeof(int);

    // zero flag + counts (adjacent -> one memset)
    hipMemsetAsync(flag, 0, (size_t)2 * N * sizeof(int), stream);

    node_logits_kernel<<<(N + 3) / 4, 256, 0, stream>>>(
        x, W, att_src, att_dst, a_src, a_dst, ids, flag, n_ids, N);

    int ethreads = (E + 3) / 4;
    hist_kernel<<<(ethreads + 255) / 256, 256, 0, stream>>>(ei, flag, counts, E);

    int nblk = (N + SCAN_B - 1) / SCAN_B;
    scan_part<<<nblk, SCAN_B, 0, stream>>>(counts, offsets, bsums, N);
    scan_mid<<<1, SCAN_B, 0, stream>>>(bsums, nblk);
    scan_add<<<nblk, SCAN_B, 0, stream>>>(offsets, cursor, bsums, N);

    scatter_kernel<<<(ethreads + 255) / 256, 256, 0, stream>>>(ei, flag, cursor, csr_src, E);

    gat_out_kernel<<<(n_ids + 3) / 4, 256, 0, stream>>>(
        x, W, a_src, a_dst, gat_bias, ln_w, ln_b, lin_W, lin_b,
        csr_src, offsets, counts, ids, out, n_ids);
}